// Round 1
// baseline (1138.325 us; speedup 1.0000x reference)
//
#include <hip/hip_runtime.h>
#include <cstddef>

#define S 512
#define SHIFT_HW 18      // 512*512 = 1<<18
#define NCOL 16384

// workspace layout (float offsets)
#define QB_OFF 0ull
#define KB_OFF 25165824ull
#define VB_OFF 50331648ull
#define G_OFF  75497472ull
#define SQ_OFF 75644928ull
#define SK_OFF 75646464ull
#define A_OFF  75648000ull
// total 75795456 floats = 303.2 MB

// ---------------------------------------------------------------------------
// K1: fused 1x1 qkv conv + 3x3 depthwise (zero pad) + scatter to blocked layout
// grid (32,32,2), block 384. 16x16 output tile, 18x18 halo.
// ---------------------------------------------------------------------------
__global__ __launch_bounds__(384) void k1_qkv_dw(
    const float* __restrict__ x, const float* __restrict__ qkv_w,
    const float* __restrict__ dw_w,
    float* __restrict__ qb, float* __restrict__ kb, float* __restrict__ vb)
{
  const int t = threadIdx.x;
  const int b = blockIdx.z;
  const int W0 = blockIdx.x * 16, H0 = blockIdx.y * 16;
  __shared__ float qs[24 * 324];   // 31.1 KB: one 24-channel group over halo

  // per-thread halo pixel, x channels held in registers across all 6 groups
  float xv[48];
  const int p  = t;
  const int hy = p / 18, hx = p % 18;            // valid for t<324
  const int Hg = H0 - 1 + hy, Wg = W0 - 1 + hx;
  const bool inb = (t < 324) && (Hg >= 0) && (Hg < S) && (Wg >= 0) && (Wg < S);
  const float* xb = x + ((size_t)b * 48 << SHIFT_HW) + (inb ? ((Hg << 9) + Wg) : 0);
  #pragma unroll
  for (int ic = 0; ic < 48; ++ic) {
    float v = 0.0f;
    if (inb) v = xb[(size_t)ic << SHIFT_HW];
    xv[ic] = v;
  }

  #pragma unroll 1
  for (int g = 0; g < 6; ++g) {
    // ---- pointwise GEMM: 24 output channels for this group, halo pixels ----
    if (t < 324) {
      const float* wgp = qkv_w + g * 24 * 48;   // uniform -> s_loads
      #pragma unroll
      for (int oc = 0; oc < 24; oc += 2) {
        float a0 = 0.f, a1 = 0.f;
        #pragma unroll
        for (int ic = 0; ic < 48; ++ic) {
          a0 += wgp[oc * 48 + ic]       * xv[ic];
          a1 += wgp[(oc + 1) * 48 + ic] * xv[ic];
        }
        qs[oc * 324 + p]       = a0;
        qs[(oc + 1) * 324 + p] = a1;
      }
    }
    __syncthreads();

    // ---- depthwise 3x3 + scatter to blocked layout ----
    const int tensor = g >> 1;            // 0=q,1=k,2=v
    const int chbase = (g & 1) * 24;
    float* dst = (tensor == 0) ? qb : (tensor == 1) ? kb : vb;
    #pragma unroll 1
    for (int r = 0; r < 16; ++r) {        // 16*384 = 6144 = 256 px * 24 ch
      const int idx = r * 384 + t;
      const int pp  = idx & 255;
      const int ch  = idx >> 8;
      const int y = pp >> 4, xq = pp & 15;
      const int chg = chbase + ch;                       // channel within tensor
      const float* dww  = dw_w + (size_t)(tensor * 48 + chg) * 9;
      const float* qrow = qs + ch * 324 + y * 18 + xq;   // halo (y, xq) == inner-1
      float s = 0.f;
      #pragma unroll
      for (int dy = 0; dy < 3; ++dy)
        #pragma unroll
        for (int dx = 0; dx < 3; ++dx)
          s += dww[dy * 3 + dx] * qrow[dy * 18 + dx];
      const int head = chg / 6, c = chg - 6 * (chg / 6);
      const int H = H0 + y, Wp = W0 + xq;
      const int row = c * 16 + (H & 3) * 4 + (Wp & 3);
      const int col = ((H >> 2) << 7) + (Wp >> 2);
      dst[(size_t)((b * 8 + head) * 96 + row) * NCOL + col] = s;
    }
    __syncthreads();
  }
}

// ---------------------------------------------------------------------------
// K3: raw Gram G[bh] = q@k^T (96x96 over K=16384) + row sum-squares, atomics.
// grid (32 chunks of 512 cols, 16 bh), block 256.
// ---------------------------------------------------------------------------
__global__ __launch_bounds__(256) void k3_gram(
    const float* __restrict__ qb, const float* __restrict__ kb,
    float* __restrict__ G, float* __restrict__ sq, float* __restrict__ sk)
{
  const int t  = threadIdx.x;
  const int bh = blockIdx.y;
  const int n0 = blockIdx.x * 512;
  __shared__ float qt[96 * 66];   // stride 66: 2-way bank aliasing only (free)
  __shared__ float kt[96 * 66];
  const int ti = t >> 4, tj = t & 15;
  float acc[6][6];
  #pragma unroll
  for (int r = 0; r < 6; ++r)
    #pragma unroll
    for (int s_ = 0; s_ < 6; ++s_) acc[r][s_] = 0.f;
  float ss = 0.f;
  const float* qbase = qb + (size_t)bh * 96 * NCOL;
  const float* kbase = kb + (size_t)bh * 96 * NCOL;
  const int srow = (t < 96) ? t : (t - 96);

  #pragma unroll 1
  for (int st = 0; st < 8; ++st) {
    const int nb = n0 + st * 64;
    __syncthreads();
    #pragma unroll
    for (int r = 0; r < 12; ++r) {          // 96x64 tile as float2 per tensor
      const int idx = r * 256 + t;
      const int row = idx >> 5, c2 = (idx & 31) * 2;
      const float2 qv = *(const float2*)(qbase + (size_t)row * NCOL + nb + c2);
      const float2 kv = *(const float2*)(kbase + (size_t)row * NCOL + nb + c2);
      *(float2*)(qt + row * 66 + c2) = qv;
      *(float2*)(kt + row * 66 + c2) = kv;
    }
    __syncthreads();
    #pragma unroll 2
    for (int nn = 0; nn < 64; nn += 2) {
      float2 qv[6], kv[6];
      #pragma unroll
      for (int r = 0; r < 6; ++r)  qv[r]  = *(const float2*)(qt + (ti * 6 + r) * 66 + nn);
      #pragma unroll
      for (int s_ = 0; s_ < 6; ++s_) kv[s_] = *(const float2*)(kt + (tj * 6 + s_) * 66 + nn);
      #pragma unroll
      for (int r = 0; r < 6; ++r)
        #pragma unroll
        for (int s_ = 0; s_ < 6; ++s_)
          acc[r][s_] += qv[r].x * kv[s_].x + qv[r].y * kv[s_].y;
    }
    if (t < 192) {                          // sum-squares for norms
      const float* base = (t < 96) ? qt : kt;
      float s2 = 0.f;
      #pragma unroll 4
      for (int nn = 0; nn < 64; ++nn) {
        const float v = base[srow * 66 + nn];
        s2 += v * v;
      }
      ss += s2;
    }
  }
  float* Gb = G + (size_t)bh * 9216;
  #pragma unroll
  for (int r = 0; r < 6; ++r)
    #pragma unroll
    for (int s_ = 0; s_ < 6; ++s_)
      atomicAdd(Gb + (ti * 6 + r) * 96 + (tj * 6 + s_), acc[r][s_]);
  if (t < 96)       atomicAdd(sq + bh * 96 + t,        ss);
  else if (t < 192) atomicAdd(sk + bh * 96 + (t - 96), ss);
}

// ---------------------------------------------------------------------------
// K4: normalize logits + per-head temperature + row softmax (96 wide).
// grid (96 rows, 16 bh), block 128.
// ---------------------------------------------------------------------------
__global__ __launch_bounds__(128) void k4_softmax(
    const float* __restrict__ G, const float* __restrict__ sq,
    const float* __restrict__ sk, const float* __restrict__ temp,
    float* __restrict__ A)
{
  const int i  = blockIdx.x;
  const int bh = blockIdx.y;
  const int h  = bh & 7;
  const int t  = threadIdx.x;
  __shared__ float red[128];

  const float nq    = fmaxf(sqrtf(sq[bh * 96 + i]), 1e-12f);
  const float scale = temp[h] / nq;
  float logit = 0.f, val = -1e30f;
  if (t < 96) {
    const float nk = fmaxf(sqrtf(sk[bh * 96 + t]), 1e-12f);
    logit = G[(size_t)bh * 9216 + i * 96 + t] * scale / nk;
    val = logit;
  }
  red[t] = val; __syncthreads();
  #pragma unroll
  for (int o = 64; o > 0; o >>= 1) {
    if (t < o) red[t] = fmaxf(red[t], red[t + o]);
    __syncthreads();
  }
  const float m = red[0]; __syncthreads();
  const float e = (t < 96) ? __expf(logit - m) : 0.f;
  red[t] = e; __syncthreads();
  #pragma unroll
  for (int o = 64; o > 0; o >>= 1) {
    if (t < o) red[t] += red[t + o];
    __syncthreads();
  }
  const float ssum = red[0];
  if (t < 96) A[(size_t)bh * 9216 + i * 96 + t] = e / ssum;
}

// ---------------------------------------------------------------------------
// K5: out = proj( from_blocks( A @ v ) ). One block = 16 attention columns
// (fixed hh, 16 consecutive ww) => output tile 4 rows x 64 cols x 48 ch.
// grid (8 wgrp, 128 hh, 2 b), block 256.
// ---------------------------------------------------------------------------
__global__ __launch_bounds__(256) void k5_av_proj(
    const float* __restrict__ vb, const float* __restrict__ A,
    const float* __restrict__ pw, float* __restrict__ out)
{
  const int t  = threadIdx.x;
  const int wg = blockIdx.x, hh = blockIdx.y, b = blockIdx.z;
  const int n0 = hh * 128 + wg * 16;
  __shared__ float vt[768 * 16];   // 49.2 KB: v[h][j][nl]
  __shared__ float ao[48 * 256];   // 49.2 KB: attn-out [ic][p][ww]

  // load v tile (float4, fully coalesced)
  #pragma unroll
  for (int r = 0; r < 12; ++r) {
    const int i4 = r * 256 + t;
    const int hj = i4 >> 2, nq = i4 & 3;
    const float4 v = *(const float4*)(vb + ((size_t)(b * 768 + hj) << 14) + n0 + nq * 4);
    *(float4*)(vt + hj * 16 + nq * 4) = v;
  }
  __syncthreads();

  // A @ v : per task 2 rows x 4 cols (8 FMA per ds_read_b128, broadcast)
  #pragma unroll 1
  for (int r = 0; r < 6; ++r) {
    const int task = r * 256 + t;           // h(8) x ip(48) x n4(4) = 1536
    const int n4 = task & 3;
    const int ip = (task >> 2) % 48;
    const int h  = task / 192;
    const int i0 = ip * 2;
    const float* arow0 = A + (size_t)((b * 8 + h) * 96 + i0) * 96;
    const float* arow1 = arow0 + 96;
    const float* vp = vt + h * 1536 + n4 * 4;
    float4 a0 = {0, 0, 0, 0}, a1 = {0, 0, 0, 0};
    #pragma unroll 4
    for (int j = 0; j < 96; ++j) {
      const float4 v4 = *(const float4*)(vp + j * 16);
      const float w0 = arow0[j], w1 = arow1[j];
      a0.x += w0 * v4.x; a0.y += w0 * v4.y; a0.z += w0 * v4.z; a0.w += w0 * v4.w;
      a1.x += w1 * v4.x; a1.y += w1 * v4.y; a1.z += w1 * v4.z; a1.w += w1 * v4.w;
    }
    const int c0 = i0 >> 4, p0 = i0 & 15;
    *(float4*)(ao + ((h * 6 + c0) * 16 + p0) * 16 + n4 * 4) = a0;
    const int i1 = i0 + 1;
    const int c1 = i1 >> 4, p1 = i1 & 15;
    *(float4*)(ao + ((h * 6 + c1) * 16 + p1) * 16 + n4 * 4) = a1;
  }
  __syncthreads();

  // proj 1x1: thread owns one output pixel across all 48 output channels
  const int xl = t & 63, ph = t >> 6;
  const int p  = ph * 4 + (xl & 3);
  const int wwl = xl >> 2;
  float sv[48];
  #pragma unroll
  for (int ic = 0; ic < 48; ++ic) sv[ic] = ao[(ic * 16 + p) * 16 + wwl];
  const int H = hh * 4 + ph;
  const int Wp = wg * 64 + xl;
  float* outp = out + ((size_t)b * 48 << SHIFT_HW) + (H << 9) + Wp;
  #pragma unroll 1
  for (int oc = 0; oc < 48; oc += 2) {
    float acc0 = 0.f, acc1 = 0.f;
    #pragma unroll
    for (int ic = 0; ic < 48; ++ic) {
      acc0 += pw[oc * 48 + ic]       * sv[ic];   // uniform -> s_loads
      acc1 += pw[(oc + 1) * 48 + ic] * sv[ic];
    }
    outp[(size_t)oc << SHIFT_HW]       = acc0;
    outp[(size_t)(oc + 1) << SHIFT_HW] = acc1;
  }
}

// ---------------------------------------------------------------------------
extern "C" void kernel_launch(void* const* d_in, const int* in_sizes, int n_in,
                              void* d_out, int out_size, void* d_ws, size_t ws_size,
                              hipStream_t stream) {
  const float* x      = (const float*)d_in[0];
  const float* qkv_w  = (const float*)d_in[1];
  const float* dw_w   = (const float*)d_in[2];
  const float* proj_w = (const float*)d_in[3];
  const float* temp   = (const float*)d_in[4];
  float* ws = (float*)d_ws;
  float* qb = ws + QB_OFF;
  float* kb = ws + KB_OFF;
  float* vb = ws + VB_OFF;
  float* G  = ws + G_OFF;
  float* sq = ws + SQ_OFF;
  float* sk = ws + SK_OFF;
  float* A  = ws + A_OFF;

  // zero G + sq + sk (contiguous region); A is fully overwritten by k4
  hipMemsetAsync(G, 0, (size_t)(147456 + 3072) * sizeof(float), stream);

  k1_qkv_dw<<<dim3(32, 32, 2), 384, 0, stream>>>(x, qkv_w, dw_w, qb, kb, vb);
  k3_gram<<<dim3(32, 16), 256, 0, stream>>>(qb, kb, G, sq, sk);
  k4_softmax<<<dim3(96, 16), 128, 0, stream>>>(G, sq, sk, temp, A);
  k5_av_proj<<<dim3(8, 128, 2), 256, 0, stream>>>(vb, A, proj_w, (float*)d_out);
}